// Round 5
// baseline (135.588 us; speedup 1.0000x reference)
//
#include <hip/hip_runtime.h>

#define NTOK 8192
#define DDIM 1024
#define NEXP 16
#define NPAIR 136   // E*(E+1)/2 pairs with e<=f
#define NREP 8      // s_glob replicas (atomic spread)

// ws layout (floats): gwT4 [4096 float4] = 16384 f | s_glob [NREP*1024] | G_part [16*136]
#define WS_GWT 0
#define WS_SG  16384
#define WS_GP  (16384 + NREP * DDIM)

// ---------------------------------------------------------------------------
// Prep: transpose gate_w [16][1024] -> gwT4[d4][e] (float4 over d, expert-
// contiguous). Also zeroes s_glob. Runs once, ~2 us.
// ---------------------------------------------------------------------------
__global__ __launch_bounds__(256) void moe_prep(
    const float* __restrict__ gate_w,
    float* __restrict__ ws)
{
    const int gid = blockIdx.x * 256 + threadIdx.x;   // 0..4095
    const int e = gid & 15;
    const int d4 = gid >> 4;                          // 0..255
    const float4* gw4 = (const float4*)gate_w;
    float4* gwT4 = (float4*)(ws + WS_GWT);
    gwT4[d4 * 16 + e] = gw4[e * 256 + d4];
    float* s_glob = ws + WS_SG;
    s_glob[gid] = 0.f;
    s_glob[gid + 4096] = 0.f;
}

// ---------------------------------------------------------------------------
// Fused: 512 blocks x 512 thr, 16 tokens/block, 2 tokens/wave.
// gwT staged in LDS ONCE per block (64 KB, shared by 8 waves) -> routing's
// gate reads are conflict-free LDS broadcasts, never L1/L2 misses; global
// gate traffic drops 8x vs per-wave streaming.
// Lane=(e:4b, h:1b, g:1b): 512-d half-dot per lane; shfl_xor(16) merges.
// Combine reads x from global (L1/L2-hot after routing) + re rows (L2).
// x^2 colsums: per-lane partials -> LDS atomics -> one global float4/thread.
// ---------------------------------------------------------------------------
__global__ __launch_bounds__(512, 4) void moe_fused(
    const float* __restrict__ x,
    const float* __restrict__ gate_b,
    const float* __restrict__ sh,
    const float* __restrict__ re,
    float* __restrict__ out,
    float* __restrict__ ws)
{
    __shared__ float gwl[NEXP * DDIM];   // 64 KB, transposed [d4][e] float4
    __shared__ float s_part[DDIM];       // 4 KB

    const int t = threadIdx.x;
    const int b = blockIdx.x;

    // stage transposed gate into LDS (coalesced both sides), zero s_part
    {
        const float4* src = (const float4*)(ws + WS_GWT);
        float4* dst = (float4*)gwl;
        #pragma unroll
        for (int k = 0; k < 8; ++k) dst[t + k * 512] = src[t + k * 512];
        s_part[t] = 0.f;
        s_part[t + 512] = 0.f;
    }
    __syncthreads();

    const int lane = t & 63;
    const int wave = t >> 6;          // 0..7
    const int e = lane & 15;
    const int h = (lane >> 4) & 1;
    const int g = lane >> 5;
    const int n0 = b * 16 + wave * 2; // 2 tokens per wave

    // ---- routing: 512-d half dot; gate from LDS (broadcast, no conflicts) ----
    const float4* xr = (const float4*)(x + (size_t)(n0 + g) * DDIM) + h * 128;
    const float4* gl = (const float4*)gwl + (size_t)h * 128 * 16 + e;
    float4 a4 = make_float4(0.f, 0.f, 0.f, 0.f);
    #pragma unroll 8
    for (int i = 0; i < 128; ++i) {
        float4 xv = xr[i];            // 4 distinct addrs/wave (16-way bcast)
        float4 gv = gl[i * 16];       // LDS: 32 distinct float4, 2-way bcast
        a4.x = fmaf(xv.x, gv.x, a4.x);
        a4.y = fmaf(xv.y, gv.y, a4.y);
        a4.z = fmaf(xv.z, gv.z, a4.z);
        a4.w = fmaf(xv.w, gv.w, a4.w);
    }
    float acc = (a4.x + a4.y) + (a4.z + a4.w);
    acc += __shfl_xor(acc, 16, 64);   // merge d-halves
    acc += gate_b[e];

    // ---- stable top2 scan over this token's 16 expert lanes (h=0 group) ----
    float v0 = -3.0e38f, v1 = -3.0e38f;
    int i0 = 0, i1 = 0;
    const int base = lane & 32;
    #pragma unroll
    for (int j = 0; j < NEXP; ++j) {
        float lv = __shfl(acc, base + j, 64);
        if (lv > v0)      { v1 = v0; i1 = i0; v0 = lv; i0 = j; }
        else if (lv > v1) { v1 = lv; i1 = j; }
    }
    float ex = __expf(v1 - v0);       // softmax denom cancels in renorm
    float w0 = 1.f / (1.f + ex);
    float w1 = ex * w0;

    // hoisted shared-expert column sums for this lane's combine slots
    float4 shs[4];
    {
        const float4* s0 = (const float4*)sh;
        const float4* s1 = (const float4*)(sh + DDIM);
        #pragma unroll
        for (int j = 0; j < 4; ++j) {
            float4 p = s0[lane + 64 * j];
            float4 q = s1[lane + 64 * j];
            shs[j] = make_float4(p.x + q.x, p.y + q.y, p.z + q.z, p.w + q.w);
        }
    }

    // ---- combine + x^2 partials ----
    float4 ss[4];
    #pragma unroll
    for (int j = 0; j < 4; ++j) ss[j] = make_float4(0.f, 0.f, 0.f, 0.f);

    #pragma unroll
    for (int tk = 0; tk < 2; ++tk) {
        const int src = tk << 5;
        float a0 = __shfl(w0, src, 64);
        float a1 = __shfl(w1, src, 64);
        int   e0 = __shfl(i0, src, 64);
        int   e1 = __shfl(i1, src, 64);
        const float4* xrow = (const float4*)(x + (size_t)(n0 + tk) * DDIM);
        const float4* r0 = (const float4*)(re + (size_t)e0 * DDIM);
        const float4* r1 = (const float4*)(re + (size_t)e1 * DDIM);
        float4* o = (float4*)(out + (size_t)(n0 + tk) * DDIM);
        #pragma unroll
        for (int j = 0; j < 4; ++j) {
            float4 xv = xrow[lane + 64 * j];
            float4 b0 = r0[lane + 64 * j];
            float4 b1 = r1[lane + 64 * j];
            float4 r;
            r.x = xv.x * (shs[j].x + a0 * b0.x + a1 * b1.x);
            r.y = xv.y * (shs[j].y + a0 * b0.y + a1 * b1.y);
            r.z = xv.z * (shs[j].z + a0 * b0.z + a1 * b1.z);
            r.w = xv.w * (shs[j].w + a0 * b0.w + a1 * b1.w);
            o[lane + 64 * j] = r;
            ss[j].x = fmaf(xv.x, xv.x, ss[j].x);
            ss[j].y = fmaf(xv.y, xv.y, ss[j].y);
            ss[j].z = fmaf(xv.z, xv.z, ss[j].z);
            ss[j].w = fmaf(xv.w, xv.w, ss[j].w);
        }
    }

    // per-lane d-slots -> block LDS reduce -> one float4 global atomic/thread
    #pragma unroll
    for (int j = 0; j < 4; ++j) {
        int d = 4 * (lane + 64 * j);
        atomicAdd(&s_part[d + 0], ss[j].x);
        atomicAdd(&s_part[d + 1], ss[j].y);
        atomicAdd(&s_part[d + 2], ss[j].z);
        atomicAdd(&s_part[d + 3], ss[j].w);
    }
    __syncthreads();
    if (t < 256) {
        float* rep = ws + WS_SG + (size_t)(b & (NREP - 1)) * DDIM;
        float4 v = ((float4*)s_part)[t];
        atomicAdd(&rep[4 * t + 0], v.x);
        atomicAdd(&rep[4 * t + 1], v.y);
        atomicAdd(&rep[4 * t + 2], v.z);
        atomicAdd(&rep[4 * t + 3], v.w);
    }
}

// ---------------------------------------------------------------------------
// Partial Gram: block b covers d-chunk [64b, 64b+64); writes G_part[b][136].
// ---------------------------------------------------------------------------
__global__ __launch_bounds__(320) void moe_div_partial(
    const float* __restrict__ re,
    float* __restrict__ ws)
{
    __shared__ float reT[64][17];
    __shared__ float s4[4][64];
    __shared__ float s_loc[64];

    const int t = threadIdx.x;
    const int b = blockIdx.x;
    const int d0 = b * 64;
    const float* s_glob = ws + WS_SG;
    float* G_part = ws + WS_GP;

    if (t < 256) {
        int c = t & 63, r = t >> 6;
        s4[r][c] = s_glob[r * DDIM + d0 + c] + s_glob[(r + 4) * DDIM + d0 + c];
        int e = t >> 4, d4 = t & 15;
        float4 v = ((const float4*)(re + (size_t)e * DDIM + d0))[d4];
        reT[d4 * 4 + 0][e] = v.x;
        reT[d4 * 4 + 1][e] = v.y;
        reT[d4 * 4 + 2][e] = v.z;
        reT[d4 * 4 + 3][e] = v.w;
    }
    __syncthreads();
    if (t < 64) s_loc[t] = (s4[0][t] + s4[1][t]) + (s4[2][t] + s4[3][t]);
    __syncthreads();

    const int p = t >> 1;
    const int half = t & 1;
    float a = 0.f;
    if (p < NPAIR) {
        int pe = 0, rem = p;
        while (rem >= NEXP - pe) { rem -= NEXP - pe; ++pe; }
        int pf = pe + rem;
        #pragma unroll
        for (int i = 0; i < 32; ++i) {
            int dd = half * 32 + i;
            a += s_loc[dd] * reT[dd][pe] * reT[dd][pf];
        }
    }
    a += __shfl_down(a, 1, 64);
    if (p < NPAIR && half == 0) G_part[b * NPAIR + p] = a;
}

// ---------------------------------------------------------------------------
// Finalize: sum 16 partial Grams, norms, clipped cosine mean * lambda.
// ---------------------------------------------------------------------------
__global__ __launch_bounds__(192) void moe_div_final(
    const float* __restrict__ ws,
    float* __restrict__ div_out)
{
    __shared__ float G[NPAIR];
    __shared__ float nr[NEXP];
    __shared__ float lsum;
    const float* G_part = ws + WS_GP;
    const int t = threadIdx.x;

    if (t == 0) lsum = 0.f;
    if (t < NPAIR) {
        float g = 0.f;
        #pragma unroll
        for (int b = 0; b < 16; ++b) g += G_part[b * NPAIR + t];
        G[t] = g;
    }
    __syncthreads();
    if (t < NEXP) {
        int idx = t * NEXP - (t * (t - 1)) / 2;   // diagonal (t,t)
        nr[t] = fmaxf(sqrtf(G[idx]), 1e-8f);
    }
    __syncthreads();
    if (t < NPAIR) {
        int pe = 0, rem = t;
        while (rem >= NEXP - pe) { rem -= NEXP - pe; ++pe; }
        int pf = pe + rem;
        if (pe != pf) {
            float sim = G[t] / (nr[pe] * nr[pf]);
            sim = fminf(1.f, fmaxf(-1.f, sim));
            atomicAdd(&lsum, 2.f * sim);
        }
    }
    __syncthreads();
    if (t == 0) *div_out = lsum / (float)(NEXP * (NEXP - 1)) * 0.1f;
}

extern "C" void kernel_launch(void* const* d_in, const int* in_sizes, int n_in,
                              void* d_out, int out_size, void* d_ws, size_t ws_size,
                              hipStream_t stream) {
    const float* x  = (const float*)d_in[0];
    const float* gw = (const float*)d_in[1];
    const float* gb = (const float*)d_in[2];
    const float* sh = (const float*)d_in[3];
    const float* re = (const float*)d_in[4];
    float* out = (float*)d_out;
    float* ws = (float*)d_ws;   // needs (16384 + 8*1024 + 16*136)*4 ~= 107 KB

    moe_prep<<<16, 256, 0, stream>>>(gw, ws);
    moe_fused<<<512, 512, 0, stream>>>(x, gb, sh, re, out, ws);
    moe_div_partial<<<16, 320, 0, stream>>>(re, ws);
    moe_div_final<<<1, 192, 0, stream>>>(ws, out + (size_t)NTOK * DDIM);
}